// Round 13
// baseline (91.001 us; speedup 1.0000x reference)
//
#include <hip/hip_runtime.h>
#include <hip/hip_bf16.h>

typedef float fx4 __attribute__((ext_vector_type(4)));
typedef short i16x8 __attribute__((ext_vector_type(8)));
typedef unsigned short u16;

#define NEG_INF_F (-9.0e15f)

__device__ inline u16 f2bf(float v){
  __hip_bfloat16 h = __float2bfloat16(v);
  return *reinterpret_cast<u16*>(&h);
}
__device__ inline unsigned pk2(float lo, float hi){
  return (unsigned)f2bf(lo) | ((unsigned)f2bf(hi) << 16);
}

// ---------------------------------------------------------------------------
// Kernel 1: Wh = x @ W (fp32), f1 = Wh@a1, f2 = Wh@a2 (fp32).
// Wh emitted bf16 in MFMA B-fragment-linear layout whB[bt][kt][ct][lane][8].
// grid (2, 96), 256 threads; thread = one node n.  (proven, unchanged)
// ---------------------------------------------------------------------------
__global__ __launch_bounds__(256) void gat_prep(
    const float* __restrict__ input,   // (8,64,12,512)
    const float* __restrict__ W,       // (64,64)
    const float* __restrict__ Avec,    // (128,1)
    u16*   __restrict__ whB,           // (96,16,4,512) bf16 fragment-linear
    float* __restrict__ f1w,           // (96,512)
    float* __restrict__ f2w)           // (96,512)
{
  __shared__ float Wl[64*64];
  __shared__ float Al[128];
  __shared__ u16   Rp[16384];
  const int tid = threadIdx.x;
  const int bt  = blockIdx.y;
  const int b   = bt / 12, t = bt % 12;
  const int xb  = blockIdx.x;
  const int n   = xb * 256 + tid;

  {
    const fx4* src = (const fx4*)W;
    fx4* dst = (fx4*)Wl;
    #pragma unroll
    for (int i = 0; i < 4; ++i) dst[tid + 256*i] = src[tid + 256*i];
    if (tid < 32) ((fx4*)Al)[tid] = ((const fx4*)Avec)[tid];
  }
  __syncthreads();

  const float* xp = input + ((size_t)b*64*12 + t) * 512 + n;

  fx4 acc[16];
  #pragma unroll
  for (int i = 0; i < 16; ++i) acc[i] = (fx4){0.f,0.f,0.f,0.f};

  #pragma unroll 8
  for (int f = 0; f < 64; ++f) {
    float xv = xp[(size_t)f * 6144];
    const fx4* wr = (const fx4*)(Wl + f*64);
    #pragma unroll
    for (int o4 = 0; o4 < 16; ++o4) acc[o4] += xv * wr[o4];
  }

  float s1 = 0.f, s2 = 0.f;
  #pragma unroll
  for (int o4 = 0; o4 < 16; ++o4) {
    fx4 v  = acc[o4];
    fx4 w1 = ((const fx4*)Al)[o4];
    fx4 w2 = ((const fx4*)Al)[o4 + 16];
    s1 += v[0]*w1[0] + v[1]*w1[1] + v[2]*w1[2] + v[3]*w1[3];
    s2 += v[0]*w2[0] + v[1]*w2[1] + v[2]*w2[2] + v[3]*w2[3];
  }
  f1w[bt*512 + n] = s1;
  f2w[bt*512 + n] = s2;

  const int ktl  = (n >> 5) & 7;
  const int q    = (n >> 3) & 3;
  const int e    = n & 7;
  const int rowb = ktl*2048 + q*128 + e;
  #pragma unroll
  for (int o4 = 0; o4 < 16; ++o4) {
    #pragma unroll
    for (int c = 0; c < 4; ++c) {
      const int o = o4*4 + c;
      Rp[rowb + (o >> 4)*512 + (o & 15)*8] = f2bf(acc[o4][c]);
    }
  }
  __syncthreads();

  uint4* dst = (uint4*)(whB + ((size_t)bt*16 + xb*8) * 2048);
  const uint4* src = (const uint4*)Rp;
  #pragma unroll
  for (int i = 0; i < 8; ++i) dst[tid + 256*i] = src[tid + 256*i];
}

// ---------------------------------------------------------------------------
// Kernel 2: single-barrier attn.  grid 1536 (96 bt x 16 chunks of 32 rows),
// 128 threads = 2 waves; wave owns 16 rows through the whole main loop.
// Compress: thread tid loads adjblk[tid + 128*i] (instr i = one full row,
// perfectly coalesced 2KB) -> nibble -> masknib[row*132 + tid] (33-word row
// stride: conflict-free strided reads). ONE barrier, then waves free-run:
// per kt, p is built directly in MFMA A-fragment registers
// (p = max(u*v_j, uh*vh_j), exact lrelu/exp algebra; bf16 AND-mask via LUT)
// and consumed by 4 PV MFMAs + 1 ones-MFMA (row sums in the C/D lanes the
// epilogue needs). Rows with MFMA-sum < 1e-30 (underflow risk / all-masked;
// ~never) redo exactly. launch_bounds (128,3): VGPR cap 170 (est peak ~130,
// no spill -- R11's (256,4)=64-cap spilled 173MB), 12 waves/CU, 6 blocks/CU.
// ---------------------------------------------------------------------------
__global__ __launch_bounds__(128, 3) void gat_attn(
    const int*   __restrict__ adj,   // (96,512,512)
    const u16*   __restrict__ whB,   // (96,16,4,512) bf16 fragment-linear
    const float* __restrict__ f1w,
    const float* __restrict__ f2w,
    float*       __restrict__ out)   // (96,512,64)
{
  __shared__ float f2l[512], ve[512], vhe[512];
  __shared__ float f1l[32];
  __shared__ float wmaxl[2];
  __shared__ uint2 lutl[16];
  __shared__ unsigned char masknib[32*132];  // [row][col4], 33-word stride

  const int tid = threadIdx.x;
  const int l   = tid & 63;
  const int w   = tid >> 6;
  const int id  = blockIdx.x;
  const int bt  = id >> 4;
  const int it  = id & 15;
  const int r   = l & 15, q = l >> 4;

  // ---- prologue part 1: f2 (+block max), f1, LUT -------------------------
  const fx4 fv = ((const fx4*)(f2w + bt*512))[tid];      // 4 f2 per thread
  ((fx4*)f2l)[tid] = fv;
  float m2 = fmaxf(fmaxf(fv[0], fv[1]), fmaxf(fv[2], fv[3]));
  #pragma unroll
  for (int off = 32; off >= 1; off >>= 1) m2 = fmaxf(m2, __shfl_xor(m2, off));
  if (l == 0) wmaxl[w] = m2;
  if (tid < 32) f1l[tid] = f1w[bt*512 + it*32 + tid];
  if (tid < 16) {
    const unsigned nb = tid;
    lutl[tid] = (uint2){ ((nb&1u)?0xFFFFu:0u) | ((nb&2u)?0xFFFF0000u:0u),
                         ((nb&4u)?0xFFFFu:0u) | ((nb&8u)?0xFFFF0000u:0u) };
  }

  // ---- adj compress: rounds of 8 coalesced row-loads, 2-deep pipeline ----
  // g = tid + 128*j  ->  row = j, col4 = tid; LDS addr = j*132 + tid.
  const uint4* adjblk = (const uint4*)(adj + ((size_t)bt*512 + it*32)*512);
  uint4 A0[8], A1[8];
  #pragma unroll
  for (int i = 0; i < 8; ++i) A0[i] = adjblk[tid + 128*i];
  #pragma unroll
  for (int i = 0; i < 8; ++i) A1[i] = adjblk[tid + 128*(8+i)];

  __syncthreads();                     // f2l/f1l/lut visible
  const float F2max = fmaxf(wmaxl[0], wmaxl[1]);
  fx4 vef, vhef;
  #pragma unroll
  for (int c = 0; c < 4; ++c) {
    vef[c]  = __expf(fv[c] - F2max);
    vhef[c] = __expf(0.2f*(fv[c] - F2max));
  }
  ((fx4*)ve)[tid]  = vef;
  ((fx4*)vhe)[tid] = vhef;

#define GAT_CONV(SRC, J0) { \
  _Pragma("unroll") for (int i = 0; i < 8; ++i) { \
    unsigned nb = 0u; \
    if ((int)SRC[i].x > 0) nb |= 1u; \
    if ((int)SRC[i].y > 0) nb |= 2u; \
    if ((int)SRC[i].z > 0) nb |= 4u; \
    if ((int)SRC[i].w > 0) nb |= 8u; \
    masknib[((J0) + i)*132 + tid] = (unsigned char)nb; } }
  GAT_CONV(A0, 0)
  #pragma unroll
  for (int i = 0; i < 8; ++i) A0[i] = adjblk[tid + 128*(16+i)];
  GAT_CONV(A1, 8)
  #pragma unroll
  for (int i = 0; i < 8; ++i) A1[i] = adjblk[tid + 128*(24+i)];
  GAT_CONV(A0, 16)
  GAT_CONV(A1, 24)
#undef GAT_CONV

  __syncthreads();                     // the ONE barrier; waves free-run now

  // ---- fused main loop: p (A-frag, in-register) -> 5 MFMAs per kt --------
  const int  row  = w*16 + r;
  const float f1v = f1l[row];
  const float tR  = f1v + F2max;
  const float M   = fmaxf(tR, 0.2f*tR);
  const float u   = __expf(tR - M);
  const float uh  = __expf(0.2f*tR - M);
  const u16* wb   = whB + (size_t)bt*32768 + l*8;
  const unsigned char* mrow = masknib + row*132;
  i16x8 bones;
  #pragma unroll
  for (int e = 0; e < 8; ++e) bones[e] = (short)0x3F80;  // bf16 1.0
  fx4 acc0 = {0,0,0,0}, acc1 = {0,0,0,0}, acc2 = {0,0,0,0}, acc3 = {0,0,0,0};
  fx4 accS = {0,0,0,0};

  #pragma unroll
  for (int kt = 0; kt < 16; ++kt) {
    const unsigned nibL = mrow[kt*8 + 2*q];
    const unsigned nibH = mrow[kt*8 + 2*q + 1];
    const fx4 a0 = ((const fx4*)ve)[kt*8 + 2*q];
    const fx4 a1 = ((const fx4*)ve)[kt*8 + 2*q + 1];
    const fx4 h0 = ((const fx4*)vhe)[kt*8 + 2*q];
    const fx4 h1 = ((const fx4*)vhe)[kt*8 + 2*q + 1];
    const uint2 mA = lutl[nibL];
    const uint2 mB = lutl[nibH];
    uint4 pw;
    pw.x = pk2(fmaxf(u*a0[0], uh*h0[0]), fmaxf(u*a0[1], uh*h0[1])) & mA.x;
    pw.y = pk2(fmaxf(u*a0[2], uh*h0[2]), fmaxf(u*a0[3], uh*h0[3])) & mA.y;
    pw.z = pk2(fmaxf(u*a1[0], uh*h1[0]), fmaxf(u*a1[1], uh*h1[1])) & mB.x;
    pw.w = pk2(fmaxf(u*a1[2], uh*h1[2]), fmaxf(u*a1[3], uh*h1[3])) & mB.y;
    const i16x8 paf = *(const i16x8*)&pw;
    const u16* bp = wb + kt*2048;
    const i16x8 b0 = *(const i16x8*)(bp);
    const i16x8 b1 = *(const i16x8*)(bp + 512);
    const i16x8 b2 = *(const i16x8*)(bp + 1024);
    const i16x8 b3 = *(const i16x8*)(bp + 1536);
    acc0 = __builtin_amdgcn_mfma_f32_16x16x32_bf16(paf, b0, acc0, 0, 0, 0);
    acc1 = __builtin_amdgcn_mfma_f32_16x16x32_bf16(paf, b1, acc1, 0, 0, 0);
    acc2 = __builtin_amdgcn_mfma_f32_16x16x32_bf16(paf, b2, acc2, 0, 0, 0);
    acc3 = __builtin_amdgcn_mfma_f32_16x16x32_bf16(paf, b3, acc3, 0, 0, 0);
    accS = __builtin_amdgcn_mfma_f32_16x16x32_bf16(paf, bones, accS, 0, 0, 0);
  }

  // ---- exact fallback (underflow-risk or all-masked rows; ~never) --------
  const bool bad = (accS[0] < 1e-30f) || (accS[1] < 1e-30f) ||
                   (accS[2] < 1e-30f) || (accS[3] < 1e-30f);
  if (__any((int)bad)) {
    float mx = NEG_INF_F;
    #pragma unroll
    for (int kt = 0; kt < 16; ++kt) {
      const unsigned mb = (unsigned)mrow[kt*8 + 2*q]
                        | ((unsigned)mrow[kt*8 + 2*q + 1] << 4);
      const fx4 g0v = ((const fx4*)f2l)[kt*8 + 2*q];
      const fx4 g1v = ((const fx4*)f2l)[kt*8 + 2*q + 1];
      mx = fmaxf(mx, (mb &   1u) ? g0v[0] : NEG_INF_F);
      mx = fmaxf(mx, (mb &   2u) ? g0v[1] : NEG_INF_F);
      mx = fmaxf(mx, (mb &   4u) ? g0v[2] : NEG_INF_F);
      mx = fmaxf(mx, (mb &   8u) ? g0v[3] : NEG_INF_F);
      mx = fmaxf(mx, (mb &  16u) ? g1v[0] : NEG_INF_F);
      mx = fmaxf(mx, (mb &  32u) ? g1v[1] : NEG_INF_F);
      mx = fmaxf(mx, (mb &  64u) ? g1v[2] : NEG_INF_F);
      mx = fmaxf(mx, (mb & 128u) ? g1v[3] : NEG_INF_F);
    }
    mx = fmaxf(mx, __shfl_xor(mx, 16));
    mx = fmaxf(mx, __shfl_xor(mx, 32));
    const float tM = f1v + mx;
    const float Mc = fmaxf(tM, 0.2f*tM);
    const float Mf = (mx == NEG_INF_F) ? NEG_INF_F : Mc;
    acc0 = acc1 = acc2 = acc3 = accS = (fx4){0,0,0,0};
    #pragma unroll
    for (int kt = 0; kt < 16; ++kt) {
      const unsigned mb = (unsigned)mrow[kt*8 + 2*q]
                        | ((unsigned)mrow[kt*8 + 2*q + 1] << 4);
      const fx4 g0v = ((const fx4*)f2l)[kt*8 + 2*q];
      const fx4 g1v = ((const fx4*)f2l)[kt*8 + 2*q + 1];
      float pv[8];
#define GAT_S(idx, bb_, ff) { float s = f1v + (ff); float lr = fmaxf(s, 0.2f*s); \
      float ee = (bb_) ? lr : NEG_INF_F; pv[idx] = __expf(ee - Mf); }
      GAT_S(0, mb &   1u, g0v[0]) GAT_S(1, mb &   2u, g0v[1])
      GAT_S(2, mb &   4u, g0v[2]) GAT_S(3, mb &   8u, g0v[3])
      GAT_S(4, mb &  16u, g1v[0]) GAT_S(5, mb &  32u, g1v[1])
      GAT_S(6, mb &  64u, g1v[2]) GAT_S(7, mb & 128u, g1v[3])
#undef GAT_S
      uint4 pw;
      pw.x = pk2(pv[0], pv[1]); pw.y = pk2(pv[2], pv[3]);
      pw.z = pk2(pv[4], pv[5]); pw.w = pk2(pv[6], pv[7]);
      const i16x8 paf = *(const i16x8*)&pw;
      const u16* bp = wb + kt*2048;
      const i16x8 b0 = *(const i16x8*)(bp);
      const i16x8 b1 = *(const i16x8*)(bp + 512);
      const i16x8 b2 = *(const i16x8*)(bp + 1024);
      const i16x8 b3 = *(const i16x8*)(bp + 1536);
      acc0 = __builtin_amdgcn_mfma_f32_16x16x32_bf16(paf, b0, acc0, 0, 0, 0);
      acc1 = __builtin_amdgcn_mfma_f32_16x16x32_bf16(paf, b1, acc1, 0, 0, 0);
      acc2 = __builtin_amdgcn_mfma_f32_16x16x32_bf16(paf, b2, acc2, 0, 0, 0);
      acc3 = __builtin_amdgcn_mfma_f32_16x16x32_bf16(paf, b3, acc3, 0, 0, 0);
      accS = __builtin_amdgcn_mfma_f32_16x16x32_bf16(paf, bones, accS, 0, 0, 0);
    }
  }

  // ---- epilogue: normalize + ELU.  C/D: col = l&15, row = q*4 + rr -------
  float* op = out + ((size_t)bt*512 + it*32 + w*16) * 64;
  #pragma unroll
  for (int rr = 0; rr < 4; ++rr) {
    const float rs = 1.0f / accS[rr];
    float v0 = acc0[rr] * rs; v0 = v0 > 0.f ? v0 : expm1f(v0);
    float v1 = acc1[rr] * rs; v1 = v1 > 0.f ? v1 : expm1f(v1);
    float v2 = acc2[rr] * rs; v2 = v2 > 0.f ? v2 : expm1f(v2);
    float v3 = acc3[rr] * rs; v3 = v3 > 0.f ? v3 : expm1f(v3);
    float* o = op + (q*4 + rr)*64 + r;
    o[ 0] = v0;
    o[16] = v1;
    o[32] = v2;
    o[48] = v3;
  }
}

// ---------------------------------------------------------------------------
extern "C" void kernel_launch(void* const* d_in, const int* in_sizes, int n_in,
                              void* d_out, int out_size, void* d_ws, size_t ws_size,
                              hipStream_t stream) {
  const float* input = (const float*)d_in[0];   // (8,64,12,512) f32
  const int*   adj   = (const int*)  d_in[1];   // (8,12,512,512) i32
  const float* W     = (const float*)d_in[2];   // (64,64) f32
  const float* Avec  = (const float*)d_in[3];   // (128,1) f32
  float* out = (float*)d_out;

  // ws: whB bf16 (6,291,456 B) | f1 (196,608) | f2 (196,608)
  char* ws = (char*)d_ws;
  u16*   whB = (u16*)ws;
  float* f1w = (float*)(ws + 6291456);
  float* f2w = (float*)(ws + 6291456 + 196608);

  gat_prep<<<dim3(2, 96), 256, 0, stream>>>(input, W, Avec, whB, f1w, f2w);
  gat_attn<<<1536, 128, 0, stream>>>(adj, whB, f1w, f2w, out);
}